// Round 6
// baseline (211.059 us; speedup 1.0000x reference)
//
#include <hip/hip_runtime.h>

#define BIGF 1e9f
#define TT 512
#define DD 256
#define NB 64
#define DROWS 1088     // diag rows per batch (1023 used + prefetch overrun pad)
#define SAK 40         // LDS row stride in bf16 (32 data + 8 pad)
#define NTILE 24       // cost tiles per batch
#define COSTB (NB * NTILE)  // 1536 cost blocks; dp blocks appended after
#define MAGIC 0x13579BDFu   // != 0xAAAAAAAA ws-poison

typedef float floatx16 __attribute__((ext_vector_type(16)));
typedef __bf16 bf16x8 __attribute__((ext_vector_type(8)));

// ---------- DPP wave shifts: lane i <- lane i-1 (shr) / lane i+1 (shl); invalid lanes get `oldv`
__device__ __forceinline__ float dpp_wave_shr1(float x, float oldv) {
  int r = __builtin_amdgcn_update_dpp(__builtin_bit_cast(int, oldv),
                                      __builtin_bit_cast(int, x),
                                      0x138, 0xF, 0xF, false);  // WAVE_SHR1
  return __builtin_bit_cast(float, r);
}
__device__ __forceinline__ float dpp_wave_shl1(float x, float oldv) {
  int r = __builtin_amdgcn_update_dpp(__builtin_bit_cast(int, oldv),
                                      __builtin_bit_cast(int, x),
                                      0x130, 0xF, 0xF, false);  // WAVE_SHL1
  return __builtin_bit_cast(float, r);
}

// ---------- Fused kernel: blocks [0,1536) = cost tiles; [1536,1600) = per-batch DP ----------
__global__ __launch_bounds__(256) void fused_kernel(const float* __restrict__ x1,
                                                    const float* __restrict__ x2,
                                                    float* __restrict__ diag,
                                                    unsigned* __restrict__ flags,
                                                    float* __restrict__ out) {
  const int n = blockIdx.x;
  if (n < COSTB) {
    // ================= cost tile path =================
    // b = n%64 -> all tiles of batch b on XCD b%8; slices m run roughly in order,
    // decoded diagonal-major (it = m/3) so low-d tiles finish first for DP pipelining.
    const int b = n & 63;
    const int m = n >> 6;       // slice 0..23
    const int it = m / 3;       // i-tile 0..7
    const int jt = m - 3 * it;  // j-tile 0..2
    const int i0 = it * 64;
    const int j0 = i0 - 50 + jt * 64;

    __shared__ __align__(16) __bf16 sA[64 * SAK];
    __shared__ __align__(16) __bf16 sB[64 * SAK];
    __shared__ float rA[64];
    __shared__ float rB[64];

    const int t = threadIdx.x;
    const int lane = t & 63;
    const int w = t >> 6;
    const int wi = w >> 1;
    const int wj = w & 1;
    const int ln = lane & 31;
    const int kh = lane >> 5;

    const int sr = t >> 2;
    const int sq = t & 3;
    const float* x1b = x1 + (size_t)b * (TT * DD);
    const float* x2b = x2 + (size_t)b * (TT * DD);
    int gj = j0 + sr;
    gj = gj < 0 ? 0 : (gj > TT - 1 ? TT - 1 : gj);
    const float* pAg = x1b + (size_t)(i0 + sr) * DD + sq * 8;
    const float* pBg = x2b + (size_t)gj * DD + sq * 8;
    __bf16* dA = sA + sr * SAK + sq * 8;
    __bf16* dB = sB + sr * SAK + sq * 8;

    const __bf16* fAp = sA + (wi * 32 + ln) * SAK + kh * 8;
    const __bf16* fBp = sB + (wj * 32 + ln) * SAK + kh * 8;

    floatx16 acc = {};
    float pa = 0.f, pb = 0.f;

    for (int kc = 0; kc < DD; kc += 32) {
      const float4 a0 = *(const float4*)(pAg + kc);
      const float4 a1 = *(const float4*)(pAg + kc + 4);
      const float4 b0 = *(const float4*)(pBg + kc);
      const float4 b1 = *(const float4*)(pBg + kc + 4);
      pa += a0.x * a0.x + a0.y * a0.y + a0.z * a0.z + a0.w * a0.w;
      pa += a1.x * a1.x + a1.y * a1.y + a1.z * a1.z + a1.w * a1.w;
      pb += b0.x * b0.x + b0.y * b0.y + b0.z * b0.z + b0.w * b0.w;
      pb += b1.x * b1.x + b1.y * b1.y + b1.z * b1.z + b1.w * b1.w;
      __syncthreads();
      {
        bf16x8 va, vb;
        va[0] = (__bf16)a0.x; va[1] = (__bf16)a0.y; va[2] = (__bf16)a0.z; va[3] = (__bf16)a0.w;
        va[4] = (__bf16)a1.x; va[5] = (__bf16)a1.y; va[6] = (__bf16)a1.z; va[7] = (__bf16)a1.w;
        vb[0] = (__bf16)b0.x; vb[1] = (__bf16)b0.y; vb[2] = (__bf16)b0.z; vb[3] = (__bf16)b0.w;
        vb[4] = (__bf16)b1.x; vb[5] = (__bf16)b1.y; vb[6] = (__bf16)b1.z; vb[7] = (__bf16)b1.w;
        *(bf16x8*)dA = va;
        *(bf16x8*)dB = vb;
      }
      __syncthreads();
      const bf16x8 fa0 = *(const bf16x8*)fAp;
      const bf16x8 fb0 = *(const bf16x8*)fBp;
      const bf16x8 fa1 = *(const bf16x8*)(fAp + 16);
      const bf16x8 fb1 = *(const bf16x8*)(fBp + 16);
      acc = __builtin_amdgcn_mfma_f32_32x32x16_bf16(fa0, fb0, acc, 0, 0, 0);
      acc = __builtin_amdgcn_mfma_f32_32x32x16_bf16(fa1, fb1, acc, 0, 0, 0);
    }

    pa += __shfl_xor(pa, 1, 64); pa += __shfl_xor(pa, 2, 64);
    pb += __shfl_xor(pb, 1, 64); pb += __shfl_xor(pb, 2, 64);
    if (sq == 0) {
      rA[sr] = 1.0f / fmaxf(sqrtf(pa), 1e-8f);
      rB[sr] = 1.0f / fmaxf(sqrtf(pb), 1e-8f);
    }
    __syncthreads();

    const int j = j0 + wj * 32 + ln;
    const float r2 = rB[wj * 32 + ln];
    float* db = diag + (size_t)b * (DROWS * 64);
#pragma unroll
    for (int reg = 0; reg < 16; ++reg) {
      const int ri = wi * 32 + (reg & 3) + 8 * (reg >> 2) + 4 * kh;
      const int i = i0 + ri;
      const int k = i - j + 50;
      if ((unsigned)j < TT && (unsigned)k <= 100) {
        const float v = 1.0f - acc[reg] * rA[ri] * r2;
        db[(size_t)(i + j) * 64 + (k >> 1)] = v;
      }
    }
    // publish: barrier drains all block stores to L2, then agent-release flag
    __syncthreads();
    if (t == 0)
      __hip_atomic_store(&flags[b * NTILE + m], MAGIC, __ATOMIC_RELEASE,
                         __HIP_MEMORY_SCOPE_AGENT);
    return;
  }

  // ================= DP path: one wave per batch =================
  const int b = n - COSTB;  // XCD (1536+b)%8 == b%8 matches producers
  if (threadIdx.x >= 64) return;
  const int l = threadIdx.x;
  float* base = diag + (size_t)b * (DROWS * 64);

  // Paint corner-invalid cells with BIG (rows d<64 and d>=972); disjoint from
  // cost's valid-cell writes, overlapped with cost execution.
  for (int r = 0; r < 180; ++r) {
    const int d = (r < 64) ? r : r + 908;
    const int p = d & 1;
    const int i = (d >> 1) + l + p - 25;
    const int j = d - i;
    const int k = 2 * l + p;
    if (k > 100 || (unsigned)i >= TT || (unsigned)j >= TT)
      base[(size_t)d * 64 + l] = BIGF;
  }

  const unsigned* fb = flags + b * NTILE;
  // pre-prologue wait: tiles it'<=1 (m=0..5) cover all d <= 206 >= prologue window 32
  if (l < 6) {
    while (__hip_atomic_load(&fb[l], __ATOMIC_RELAXED, __HIP_MEMORY_SCOPE_AGENT) != MAGIC)
      __builtin_amdgcn_s_sleep(8);
  }
  __asm__ __volatile__("" ::: "memory");  // pin load order; HW ordered by control dep

  const float* pO = base + 64 + l;   // d = 1
  const float* pE = base + 128 + l;  // d = 2
  float cr[32];
#pragma unroll
  for (int t2 = 0; t2 < 16; ++t2) {
    cr[2 * t2] = *pO; pO += 128;
    cr[2 * t2 + 1] = *pE; pE += 128;
  }
  float prev2 = BIGF;
  const float c00 = base[25];
  float prev1 = (l == 25) ? c00 : BIGF;
  const bool inv_odd = (l >= 50);
  const bool inv_even = (l >= 51);
  const int I = l / 3;              // producer tile index for lane-as-flag-poller
  float ans = BIGF;

  for (int it2 = 0; it2 < 32; ++it2) {
    // staggered wait: tile I first touched by prefetch window at it2 = 4I-4
    if (l >= 6 && l < 24 && it2 == 4 * I - 4) {
      while (__hip_atomic_load(&fb[l], __ATOMIC_RELAXED, __HIP_MEMORY_SCOPE_AGENT) != MAGIC)
        __builtin_amdgcn_s_sleep(8);
    }
    __asm__ __volatile__("" ::: "memory");
#pragma unroll
    for (int u = 0; u < 16; ++u) {
      // odd diagonal
      const float c1 = inv_odd ? BIGF : cr[2 * u];
      cr[2 * u] = *pO; pO += 128;  // prefetch 32 diagonals ahead
      const float sh = dpp_wave_shl1(prev1, BIGF);
      const float m3 = fminf(fminf(prev1, sh), prev2);
      prev2 = prev1;
      prev1 = c1 + m3;
      // even diagonal
      const float c2 = inv_even ? BIGF : cr[2 * u + 1];
      cr[2 * u + 1] = *pE; pE += 128;
      const float sh2 = dpp_wave_shr1(prev1, BIGF);
      const float m32 = fminf(fminf(sh2, prev1), prev2);
      prev2 = prev1;
      prev1 = c2 + m32;
      if (u == 14 && it2 == 31) ans = prev1;  // d = 1022 -> cell (511,511) at lane 25
    }
  }
  if (l == 25) out[b] = ans;
}

extern "C" void kernel_launch(void* const* d_in, const int* in_sizes, int n_in,
                              void* d_out, int out_size, void* d_ws, size_t ws_size,
                              hipStream_t stream) {
  const float* x1 = (const float*)d_in[0];
  const float* x2 = (const float*)d_in[1];
  float* out = (float*)d_out;
  float* diag = (float*)d_ws;                               // 64*1088*64 floats = 17.8 MB
  unsigned* flags = (unsigned*)(diag + (size_t)NB * DROWS * 64);  // 64*24 words

  fused_kernel<<<COSTB + NB, 256, 0, stream>>>(x1, x2, diag, flags, out);
}

// Round 7
// 139.304 us; speedup vs baseline: 1.5151x; 1.5151x over previous
//
#include <hip/hip_runtime.h>

#define BIGF 1e9f
#define TT 512
#define DD 256
#define NB 64
#define DROWS 1088    // diag rows per batch (1023 used + prefetch overrun pad)
#define SAK 40        // LDS row stride in bf16 (32 data + 8 pad)

typedef float floatx16 __attribute__((ext_vector_type(16)));
typedef __bf16 bf16x8 __attribute__((ext_vector_type(8)));

// ---------- DPP wave shifts: lane i <- lane i-1 (shr) / lane i+1 (shl); invalid lanes get `oldv`
__device__ __forceinline__ float dpp_wave_shr1(float x, float oldv) {
  int r = __builtin_amdgcn_update_dpp(__builtin_bit_cast(int, oldv),
                                      __builtin_bit_cast(int, x),
                                      0x138, 0xF, 0xF, false);  // WAVE_SHR1
  return __builtin_bit_cast(float, r);
}
__device__ __forceinline__ float dpp_wave_shl1(float x, float oldv) {
  int r = __builtin_amdgcn_update_dpp(__builtin_bit_cast(int, oldv),
                                      __builtin_bit_cast(int, x),
                                      0x130, 0xF, 0xF, false);  // WAVE_SHL1
  return __builtin_bit_cast(float, r);
}

// ---------- Kernel B: banded cost via bf16 MFMA + fused norms, written in diag layout ----------
// 64x64 (i,j) tile per block; 4 waves in 2x2; each wave one 32x32 MFMA accumulator.
// Grid is 1D, decoded so all 24 tiles of batch b share XCD b%8 (block n -> XCD n%8 heuristic):
// x1/x2 of a batch stay L2-resident -> fetch ~= compulsory 67 MB.
__global__ __launch_bounds__(256) void cost_kernel(const float* __restrict__ x1,
                                                   const float* __restrict__ x2,
                                                   float* __restrict__ diag) {
  const int n = blockIdx.x;
  const int b = n & 63;       // batch; b%8 == n%8 -> XCD
  const int m = n >> 6;       // 0..23
  const int it = m & 7;       // i-tile
  const int jt = m >> 3;      // j-tile 0..2
  const int i0 = it * 64;
  const int j0 = i0 - 50 + jt * 64;

  __shared__ __align__(16) __bf16 sA[64 * SAK];
  __shared__ __align__(16) __bf16 sB[64 * SAK];
  __shared__ float rA[64];  // 1/max(||x1_i||, eps) per tile row
  __shared__ float rB[64];

  const int t = threadIdx.x;
  const int lane = t & 63;
  const int w = t >> 6;       // wave 0..3
  const int wi = w >> 1;      // i-subtile (0/1)
  const int wj = w & 1;       // j-subtile (0/1)
  const int ln = lane & 31;
  const int kh = lane >> 5;   // k-half (0/1)

  // staging mapping: thread t loads row (t>>2), 8 floats at quarter (t&3)
  const int sr = t >> 2;
  const int sq = t & 3;
  const float* x1b = x1 + (size_t)b * (TT * DD);
  const float* x2b = x2 + (size_t)b * (TT * DD);
  int gj = j0 + sr;
  gj = gj < 0 ? 0 : (gj > TT - 1 ? TT - 1 : gj);
  const float* pAg = x1b + (size_t)(i0 + sr) * DD + sq * 8;
  const float* pBg = x2b + (size_t)gj * DD + sq * 8;
  __bf16* dA = sA + sr * SAK + sq * 8;
  __bf16* dB = sB + sr * SAK + sq * 8;

  const __bf16* fAp = sA + (wi * 32 + ln) * SAK + kh * 8;
  const __bf16* fBp = sB + (wj * 32 + ln) * SAK + kh * 8;

  floatx16 acc = {};
  float pa = 0.f, pb = 0.f;  // sum-of-squares partials (fp32, from original data)

  for (int kc = 0; kc < DD; kc += 32) {
    const float4 a0 = *(const float4*)(pAg + kc);
    const float4 a1 = *(const float4*)(pAg + kc + 4);
    const float4 b0 = *(const float4*)(pBg + kc);
    const float4 b1 = *(const float4*)(pBg + kc + 4);
    pa += a0.x * a0.x + a0.y * a0.y + a0.z * a0.z + a0.w * a0.w;
    pa += a1.x * a1.x + a1.y * a1.y + a1.z * a1.z + a1.w * a1.w;
    pb += b0.x * b0.x + b0.y * b0.y + b0.z * b0.z + b0.w * b0.w;
    pb += b1.x * b1.x + b1.y * b1.y + b1.z * b1.z + b1.w * b1.w;
    __syncthreads();
    {
      bf16x8 va, vb;
      va[0] = (__bf16)a0.x; va[1] = (__bf16)a0.y; va[2] = (__bf16)a0.z; va[3] = (__bf16)a0.w;
      va[4] = (__bf16)a1.x; va[5] = (__bf16)a1.y; va[6] = (__bf16)a1.z; va[7] = (__bf16)a1.w;
      vb[0] = (__bf16)b0.x; vb[1] = (__bf16)b0.y; vb[2] = (__bf16)b0.z; vb[3] = (__bf16)b0.w;
      vb[4] = (__bf16)b1.x; vb[5] = (__bf16)b1.y; vb[6] = (__bf16)b1.z; vb[7] = (__bf16)b1.w;
      *(bf16x8*)dA = va;
      *(bf16x8*)dB = vb;
    }
    __syncthreads();
    const bf16x8 fa0 = *(const bf16x8*)fAp;
    const bf16x8 fb0 = *(const bf16x8*)fBp;
    const bf16x8 fa1 = *(const bf16x8*)(fAp + 16);
    const bf16x8 fb1 = *(const bf16x8*)(fBp + 16);
    acc = __builtin_amdgcn_mfma_f32_32x32x16_bf16(fa0, fb0, acc, 0, 0, 0);
    acc = __builtin_amdgcn_mfma_f32_32x32x16_bf16(fa1, fb1, acc, 0, 0, 0);
  }

  // reduce sumsq across the 4 staging threads of each row (lanes t^1, t^2 share sr)
  pa += __shfl_xor(pa, 1, 64); pa += __shfl_xor(pa, 2, 64);
  pb += __shfl_xor(pb, 1, 64); pb += __shfl_xor(pb, 2, 64);
  if (sq == 0) {
    rA[sr] = 1.0f / fmaxf(sqrtf(pa), 1e-8f);
    rB[sr] = 1.0f / fmaxf(sqrtf(pb), 1e-8f);
  }
  __syncthreads();

  // epilogue: C layout col=lane&31 (j), row=(reg&3)+8*(reg>>2)+4*(lane>>5) (i)
  // write directly to diag[b][d=i+j][l=(i-j+50)>>1]
  const int j = j0 + wj * 32 + ln;
  const float r2 = rB[wj * 32 + ln];
  float* db = diag + (size_t)b * (DROWS * 64);
#pragma unroll
  for (int reg = 0; reg < 16; ++reg) {
    const int ri = wi * 32 + (reg & 3) + 8 * (reg >> 2) + 4 * kh;
    const int i = i0 + ri;
    const int k = i - j + 50;
    if ((unsigned)j < TT && (unsigned)k <= 100) {
      const float v = 1.0f - acc[reg] * rA[ri] * r2;
      db[(size_t)(i + j) * 64 + (k >> 1)] = v;
    }
  }
}

// ---------- Kernel C: corner paint + anti-diagonal DP, one wave per batch ----------
// Band offset k = i-j+50; lane l holds cell k = 2l+p (p = d&1).
// new[k] = c + min(prev1[k-1], prev1[k+1], prev2[k])
//   p=1 (odd d): k-1 -> same lane, k+1 -> wave_shl1;  p=0: k-1 -> wave_shr1, k+1 -> same lane.
// Middle diagonals (64<=d<972): every l<=50 cell is cost-written; l>=51 (and l==50 odd)
// masked arithmetically. Corner diagonals (d<64, d>=972): this block paints the
// invalid cells BIG itself (disjoint from cost's valid-cell writes; stream-ordered
// after cost, so no race), then drains vmcnt before the ring prologue reads them.
__global__ __launch_bounds__(64) void dtw_dp_kernel(const float* __restrict__ diag,
                                                    float* __restrict__ out) {
  const int b = blockIdx.x;
  const int l = threadIdx.x;
  float* base = (float*)diag + (size_t)b * (DROWS * 64);

  // paint corner-invalid cells (poison 0xAA decodes to -3e-13 and must not leak in)
  for (int r = 0; r < 180; ++r) {
    const int d = (r < 64) ? r : r + 908;  // [0,64) U [972,1088)
    const int p = d & 1;
    const int i = (d >> 1) + l + p - 25;
    const int j = d - i;
    const int k = 2 * l + p;
    if (k > 100 || (unsigned)i >= TT || (unsigned)j >= TT)
      base[(size_t)d * 64 + l] = BIGF;
  }
  __builtin_amdgcn_s_waitcnt(0);  // own stores complete before ring loads below

  const bool inv_odd = (l >= 50);   // k=2l+1 > 100
  const bool inv_even = (l >= 51);  // k=2l   > 100
  const float* pO = base + 64 + l;   // d = 1
  const float* pE = base + 128 + l;  // d = 2
  float cr[32];
#pragma unroll
  for (int t = 0; t < 16; ++t) {
    cr[2 * t] = *pO; pO += 128;
    cr[2 * t + 1] = *pE; pE += 128;
  }
  float prev2 = BIGF;
  const float c00 = base[25];          // cost(0,0) lives at d=0, lane 25
  float prev1 = (l == 25) ? c00 : BIGF;
  float ans = BIGF;
  for (int it = 0; it < 32; ++it) {
#pragma unroll
    for (int u = 0; u < 16; ++u) {
      // odd diagonal
      const float c1 = inv_odd ? BIGF : cr[2 * u];
      cr[2 * u] = *pO; pO += 128;  // prefetch d+64 (stays within DROWS pad)
      const float sh = dpp_wave_shl1(prev1, BIGF);
      const float m3 = fminf(fminf(prev1, sh), prev2);
      prev2 = prev1;
      prev1 = c1 + m3;
      // even diagonal
      const float c2 = inv_even ? BIGF : cr[2 * u + 1];
      cr[2 * u + 1] = *pE; pE += 128;
      const float sh2 = dpp_wave_shr1(prev1, BIGF);
      const float m32 = fminf(fminf(sh2, prev1), prev2);
      prev2 = prev1;
      prev1 = c2 + m32;
      if (u == 14 && it == 31) ans = prev1;  // d = 1022 -> cell (511,511) at lane 25
    }
  }
  if (l == 25) out[b] = ans;
}

extern "C" void kernel_launch(void* const* d_in, const int* in_sizes, int n_in,
                              void* d_out, int out_size, void* d_ws, size_t ws_size,
                              hipStream_t stream) {
  const float* x1 = (const float*)d_in[0];
  const float* x2 = (const float*)d_in[1];
  float* out = (float*)d_out;
  float* diag = (float*)d_ws;  // 64*1088*64 floats = 17.8 MB

  cost_kernel<<<NB * 24, 256, 0, stream>>>(x1, x2, diag);
  dtw_dp_kernel<<<NB, 64, 0, stream>>>(diag, out);
}

// Round 8
// 128.022 us; speedup vs baseline: 1.6486x; 1.0881x over previous
//
#include <hip/hip_runtime.h>

#define BIGF 1e9f
#define TT 512
#define DD 256
#define NB 64
#define DROWS 1088    // diag rows per batch (1023 used + prefetch overrun pad)
#define SAK 40        // LDS row stride in bf16 (32 data + 8 pad)

typedef float floatx16 __attribute__((ext_vector_type(16)));
typedef __bf16 bf16x8 __attribute__((ext_vector_type(8)));

// ---------- DPP wave shifts: lane i <- lane i-1 (shr) / lane i+1 (shl); invalid lanes get `oldv`
__device__ __forceinline__ float dpp_wave_shr1(float x, float oldv) {
  int r = __builtin_amdgcn_update_dpp(__builtin_bit_cast(int, oldv),
                                      __builtin_bit_cast(int, x),
                                      0x138, 0xF, 0xF, false);  // WAVE_SHR1
  return __builtin_bit_cast(float, r);
}
__device__ __forceinline__ float dpp_wave_shl1(float x, float oldv) {
  int r = __builtin_amdgcn_update_dpp(__builtin_bit_cast(int, oldv),
                                      __builtin_bit_cast(int, x),
                                      0x130, 0xF, 0xF, false);  // WAVE_SHL1
  return __builtin_bit_cast(float, r);
}

// ---------- Kernel B: banded cost via bf16 MFMA + fused norms, written in diag layout ----------
// 64x64 (i,j) tile per block; 4 waves in 2x2; each wave one 32x32 MFMA accumulator.
// Grid is 1D, decoded so all 24 tiles of batch b share XCD b%8 (block n -> XCD n%8 heuristic):
// x1/x2 of a batch stay L2-resident -> fetch ~= compulsory 67 MB.
// m==0 blocks additionally paint their batch's corner-invalid diag cells with BIG
// (d<64 and d>=972 rows where poison 0xAA = -3e-13 would otherwise leak into the DP).
// Painted cells are disjoint from every block's valid-cell writes -> no sync needed.
__global__ __launch_bounds__(256) void cost_kernel(const float* __restrict__ x1,
                                                   const float* __restrict__ x2,
                                                   float* __restrict__ diag) {
  const int n = blockIdx.x;
  const int b = n & 63;       // batch; b%8 == n%8 -> XCD
  const int m = n >> 6;       // 0..23
  const int it = m & 7;       // i-tile
  const int jt = m >> 3;      // j-tile 0..2
  const int i0 = it * 64;
  const int j0 = i0 - 50 + jt * 64;

  __shared__ __align__(16) __bf16 sA[64 * SAK];
  __shared__ __align__(16) __bf16 sB[64 * SAK];
  __shared__ float rA[64];  // 1/max(||x1_i||, eps) per tile row
  __shared__ float rB[64];

  const int t = threadIdx.x;
  const int lane = t & 63;
  const int w = t >> 6;       // wave 0..3
  const int wi = w >> 1;      // i-subtile (0/1)
  const int wj = w & 1;       // j-subtile (0/1)
  const int ln = lane & 31;
  const int kh = lane >> 5;   // k-half (0/1)

  float* db = diag + (size_t)b * (DROWS * 64);

  // corner paint (one block per batch; overlapped with the other 1472 blocks' compute)
  if (m == 0) {
    for (int r = w; r < 180; r += 4) {
      const int d = (r < 64) ? r : r + 908;  // [0,64) U [972,1088)
      const int p = d & 1;
      const int i = (d >> 1) + lane + p - 25;
      const int j = d - i;
      const int k = 2 * lane + p;
      if (k > 100 || (unsigned)i >= TT || (unsigned)j >= TT)
        db[(size_t)d * 64 + lane] = BIGF;
    }
  }

  // staging mapping: thread t loads row (t>>2), 8 floats at quarter (t&3)
  const int sr = t >> 2;
  const int sq = t & 3;
  const float* x1b = x1 + (size_t)b * (TT * DD);
  const float* x2b = x2 + (size_t)b * (TT * DD);
  int gj = j0 + sr;
  gj = gj < 0 ? 0 : (gj > TT - 1 ? TT - 1 : gj);
  const float* pAg = x1b + (size_t)(i0 + sr) * DD + sq * 8;
  const float* pBg = x2b + (size_t)gj * DD + sq * 8;
  __bf16* dA = sA + sr * SAK + sq * 8;
  __bf16* dB = sB + sr * SAK + sq * 8;

  const __bf16* fAp = sA + (wi * 32 + ln) * SAK + kh * 8;
  const __bf16* fBp = sB + (wj * 32 + ln) * SAK + kh * 8;

  floatx16 acc = {};
  float pa = 0.f, pb = 0.f;  // sum-of-squares partials (fp32, from original data)

  for (int kc = 0; kc < DD; kc += 32) {
    const float4 a0 = *(const float4*)(pAg + kc);
    const float4 a1 = *(const float4*)(pAg + kc + 4);
    const float4 b0 = *(const float4*)(pBg + kc);
    const float4 b1 = *(const float4*)(pBg + kc + 4);
    pa += a0.x * a0.x + a0.y * a0.y + a0.z * a0.z + a0.w * a0.w;
    pa += a1.x * a1.x + a1.y * a1.y + a1.z * a1.z + a1.w * a1.w;
    pb += b0.x * b0.x + b0.y * b0.y + b0.z * b0.z + b0.w * b0.w;
    pb += b1.x * b1.x + b1.y * b1.y + b1.z * b1.z + b1.w * b1.w;
    __syncthreads();
    {
      bf16x8 va, vb;
      va[0] = (__bf16)a0.x; va[1] = (__bf16)a0.y; va[2] = (__bf16)a0.z; va[3] = (__bf16)a0.w;
      va[4] = (__bf16)a1.x; va[5] = (__bf16)a1.y; va[6] = (__bf16)a1.z; va[7] = (__bf16)a1.w;
      vb[0] = (__bf16)b0.x; vb[1] = (__bf16)b0.y; vb[2] = (__bf16)b0.z; vb[3] = (__bf16)b0.w;
      vb[4] = (__bf16)b1.x; vb[5] = (__bf16)b1.y; vb[6] = (__bf16)b1.z; vb[7] = (__bf16)b1.w;
      *(bf16x8*)dA = va;
      *(bf16x8*)dB = vb;
    }
    __syncthreads();
    const bf16x8 fa0 = *(const bf16x8*)fAp;
    const bf16x8 fb0 = *(const bf16x8*)fBp;
    const bf16x8 fa1 = *(const bf16x8*)(fAp + 16);
    const bf16x8 fb1 = *(const bf16x8*)(fBp + 16);
    acc = __builtin_amdgcn_mfma_f32_32x32x16_bf16(fa0, fb0, acc, 0, 0, 0);
    acc = __builtin_amdgcn_mfma_f32_32x32x16_bf16(fa1, fb1, acc, 0, 0, 0);
  }

  // reduce sumsq across the 4 staging threads of each row (lanes t^1, t^2 share sr)
  pa += __shfl_xor(pa, 1, 64); pa += __shfl_xor(pa, 2, 64);
  pb += __shfl_xor(pb, 1, 64); pb += __shfl_xor(pb, 2, 64);
  if (sq == 0) {
    rA[sr] = 1.0f / fmaxf(sqrtf(pa), 1e-8f);
    rB[sr] = 1.0f / fmaxf(sqrtf(pb), 1e-8f);
  }
  __syncthreads();

  // epilogue: C layout col=lane&31 (j), row=(reg&3)+8*(reg>>2)+4*(lane>>5) (i)
  // write directly to diag[b][d=i+j][l=(i-j+50)>>1]
  const int j = j0 + wj * 32 + ln;
  const float r2 = rB[wj * 32 + ln];
#pragma unroll
  for (int reg = 0; reg < 16; ++reg) {
    const int ri = wi * 32 + (reg & 3) + 8 * (reg >> 2) + 4 * kh;
    const int i = i0 + ri;
    const int k = i - j + 50;
    if ((unsigned)j < TT && (unsigned)k <= 100) {
      const float v = 1.0f - acc[reg] * rA[ri] * r2;
      db[(size_t)(i + j) * 64 + (k >> 1)] = v;
    }
  }
}

// ---------- Kernel C: anti-diagonal DP, one wave per batch, coalesced diag reads ----------
// Band offset k = i-j+50; lane l holds cell k = 2l+p (p = d&1).
// new[k] = c + min(prev1[k-1], prev1[k+1], prev2[k])
//   p=1 (odd d): k-1 -> same lane, k+1 -> wave_shl1;  p=0: k-1 -> wave_shr1, k+1 -> same lane.
// Lanes l>=51 (and l==50 on odd d) are permanently out of band: their cost is forced
// to BIG via a loop-invariant cndmask on the prefetched value (off the critical chain);
// corner diagonals were BIG-painted by cost_kernel's m==0 blocks.
__global__ __launch_bounds__(64) void dtw_dp_kernel(const float* __restrict__ diag,
                                                    float* __restrict__ out) {
  const int b = blockIdx.x;
  const int l = threadIdx.x;
  const bool inv_odd = (l >= 50);   // k=2l+1 > 100
  const bool inv_even = (l >= 51);  // k=2l   > 100
  const float* base = diag + (size_t)b * (DROWS * 64);
  const float* pO = base + 64 + l;   // d = 1
  const float* pE = base + 128 + l;  // d = 2
  float cr[32];
#pragma unroll
  for (int t = 0; t < 16; ++t) {
    cr[2 * t] = *pO; pO += 128;
    cr[2 * t + 1] = *pE; pE += 128;
  }
  float prev2 = BIGF;
  const float c00 = base[25];          // cost(0,0) lives at d=0, lane 25
  float prev1 = (l == 25) ? c00 : BIGF;
  float ans = BIGF;
  for (int it = 0; it < 32; ++it) {
#pragma unroll
    for (int u = 0; u < 16; ++u) {
      // odd diagonal
      const float c1 = inv_odd ? BIGF : cr[2 * u];
      cr[2 * u] = *pO; pO += 128;  // prefetch 32 diagonals ahead (stays within DROWS pad)
      const float sh = dpp_wave_shl1(prev1, BIGF);
      const float m3 = fminf(fminf(prev1, sh), prev2);
      prev2 = prev1;
      prev1 = c1 + m3;
      // even diagonal
      const float c2 = inv_even ? BIGF : cr[2 * u + 1];
      cr[2 * u + 1] = *pE; pE += 128;
      const float sh2 = dpp_wave_shr1(prev1, BIGF);
      const float m32 = fminf(fminf(sh2, prev1), prev2);
      prev2 = prev1;
      prev1 = c2 + m32;
      if (u == 14 && it == 31) ans = prev1;  // d = 1022 -> cell (511,511) at lane 25
    }
  }
  if (l == 25) out[b] = ans;
}

extern "C" void kernel_launch(void* const* d_in, const int* in_sizes, int n_in,
                              void* d_out, int out_size, void* d_ws, size_t ws_size,
                              hipStream_t stream) {
  const float* x1 = (const float*)d_in[0];
  const float* x2 = (const float*)d_in[1];
  float* out = (float*)d_out;
  float* diag = (float*)d_ws;  // 64*1088*64 floats = 17.8 MB

  cost_kernel<<<NB * 24, 256, 0, stream>>>(x1, x2, diag);
  dtw_dp_kernel<<<NB, 64, 0, stream>>>(diag, out);
}